// Round 1
// baseline (241.612 us; speedup 1.0000x reference)
//
#include <hip/hip_runtime.h>
#include <math.h>

#define NCLS 1000
#define MT 33
#define D 1024
#define BETA 5.5f

__device__ __forceinline__ float wave_sum(float v) {
#pragma unroll
  for (int off = 32; off; off >>= 1) v += __shfl_xor(v, off, 64);
  return v;
}

__device__ __forceinline__ float dot4(float4 a, float4 b) {
  return a.x * b.x + a.y * b.y + a.z * b.z + a.w * b.w;
}
__device__ __forceinline__ float sum4(float4 a) { return a.x + a.y + a.z + a.w; }

// block of 1024 threads (16 waves); scr must hold >=17 floats
__device__ __forceinline__ float block_sum16(float v, volatile float* scr) {
  v = wave_sum(v);
  const int wv = threadIdx.x >> 6, lane = threadIdx.x & 63;
  if (lane == 0) scr[wv] = v;
  __syncthreads();
  if (wv == 0) {
    float x = (lane < 16) ? scr[lane] : 0.0f;
#pragma unroll
    for (int off = 8; off; off >>= 1) x += __shfl_xor(x, off, 64);
    if (lane == 0) scr[16] = x;
  }
  __syncthreads();
  return scr[16];
}

__global__ __launch_bounds__(1024) void zero_kernel(float* __restrict__ s) {
  s[threadIdx.x] = 0.0f;
}

// column sum of global_bias [NCLS, D] into s[D] (s pre-zeroed)
__global__ __launch_bounds__(1024) void colsum_kernel(const float* __restrict__ gb,
                                                      float* __restrict__ s) {
  const int t = threadIdx.x;
  float p = 0.0f;
  for (int c = blockIdx.x; c < NCLS; c += gridDim.x) p += gb[(size_t)c * D + t];
  atomicAdd(&s[t], p);
}

// q = l2norm(img + s/NCLS)
__global__ __launch_bounds__(1024) void qnorm_kernel(const float* __restrict__ img,
                                                     const float* __restrict__ s,
                                                     float* __restrict__ q) {
  __shared__ float scr[17];
  const int t = threadIdx.x;
  const float v = img[t] + s[t] * (1.0f / (float)NCLS);
  const float ss = block_sum16(v * v, scr);
  q[t] = v / sqrtf(ss);
}

__global__ __launch_bounds__(1024) void main_kernel(
    const float* __restrict__ memp, const float* __restrict__ gbk,
    const float* __restrict__ gbv, const float* __restrict__ gffn,
    const float* __restrict__ img, const float* __restrict__ qvec,
    const float* __restrict__ ls, float* __restrict__ logits) {
  __shared__ float red[8 * D];  // 32 KB tree-reduce buffer / a_raw store
  __shared__ float scr[17];
  const int c = blockIdx.x;
  const int t = threadIdx.x;
  const int wv = t >> 6, lane = t & 63;
  const int dbase = lane * 4;

  const float* gbk_c = gbk + (size_t)c * D;
  const float* gbv_c = gbv + (size_t)c * D;

  // per-thread register slices of q, gbk_c, gbv_c (same d-map for all waves)
  float4 qv[4], kv[4], vvr[4];
#pragma unroll
  for (int k = 0; k < 4; ++k) {
    const int d = k * 256 + dbase;
    qv[k] = *(const float4*)(qvec + d);
    kv[k] = *(const float4*)(gbk_c + d);
    vvr[k] = *(const float4*)(gbv_c + d);
  }
  // per-class scalars: ||gbk||^2, ||gbv||^2, q.gbk  (each wave computes redundantly)
  float kk = 0.0f, vv2 = 0.0f, qk = 0.0f;
#pragma unroll
  for (int k = 0; k < 4; ++k) {
    kk += dot4(kv[k], kv[k]);
    vv2 += dot4(vvr[k], vvr[k]);
    qk += dot4(qv[k], kv[k]);
  }
  kk = wave_sum(kk);
  vv2 = wave_sum(vv2);
  qk = wave_sum(qk);

  float4 acc[4];
#pragma unroll
  for (int k = 0; k < 4; ++k) acc[k] = make_float4(0.f, 0.f, 0.f, 0.f);
  float Wsum = 0.0f;

  const float* memc = memp + (size_t)c * MT * D;
  for (int m = wv; m < MT; m += 16) {
    float4 mv[4];
#pragma unroll
    for (int k = 0; k < 4; ++k)
      mv[k] = *(const float4*)(memc + (size_t)m * D + k * 256 + dbase);
    float pqm = 0.f, pkm = 0.f, pvm = 0.f, pmm = 0.f, ps = 0.f;
#pragma unroll
    for (int k = 0; k < 4; ++k) {
      pqm += dot4(qv[k], mv[k]);
      pkm += dot4(kv[k], mv[k]);
      pvm += dot4(vvr[k], mv[k]);
      pmm += dot4(mv[k], mv[k]);
      ps += sum4(mv[k]);
    }
    pqm = wave_sum(pqm);
    pkm = wave_sum(pkm);
    pvm = wave_sum(pvm);
    pmm = wave_sum(pmm);
    ps = wave_sum(ps);

    const float nk = sqrtf(pmm + 2.0f * pkm + kk);
    const float cosv = (pqm + qk) / nk;
    const float sim = expf(-BETA * (1.0f - cosv));
    const float nv = sqrtf(pmm + 2.0f * pvm + vv2);
    const float wgt = (ps == 0.0f) ? 0.0f : sim / nv;
    Wsum += wgt;
#pragma unroll
    for (int k = 0; k < 4; ++k) {
      acc[k].x += wgt * mv[k].x;
      acc[k].y += wgt * mv[k].y;
      acc[k].z += wgt * mv[k].z;
      acc[k].w += wgt * mv[k].w;
    }
  }
  // fold (sum_m w_m) * gbv into each wave's partial (linear, sums correctly)
#pragma unroll
  for (int k = 0; k < 4; ++k) {
    acc[k].x += Wsum * vvr[k].x;
    acc[k].y += Wsum * vvr[k].y;
    acc[k].z += Wsum * vvr[k].z;
    acc[k].w += Wsum * vvr[k].w;
  }

  // tree-reduce the 16 per-wave partial a_raw vectors (d = k*256 + lane*4 + j)
#pragma unroll
  for (int half = 8; half >= 1; half >>= 1) {
    if (wv >= half && wv < 2 * half) {
      float* dst = red + (wv - half) * D + dbase;
#pragma unroll
      for (int k = 0; k < 4; ++k) *(float4*)(dst + k * 256) = acc[k];
    }
    __syncthreads();
    if (wv < half) {
      const float* src = red + wv * D + dbase;
#pragma unroll
      for (int k = 0; k < 4; ++k) {
        const float4 t4 = *(const float4*)(src + k * 256);
        acc[k].x += t4.x;
        acc[k].y += t4.y;
        acc[k].z += t4.z;
        acc[k].w += t4.w;
      }
    }
    __syncthreads();
  }
  if (wv == 0) {
#pragma unroll
    for (int k = 0; k < 4; ++k) *(float4*)(red + k * 256 + dbase) = acc[k];
  }
  __syncthreads();

  // stage 2: double l2norm + dot with img
  const float araw = red[t];
  const float n1sq = block_sum16(araw * araw, scr);
  const float a1 = araw / sqrtf(n1sq) + gffn[(size_t)c * D + t];
  const float n2sq = block_sum16(a1 * a1, scr);
  const float d3 = block_sum16(a1 * img[t], scr);
  if (t == 0) logits[c] = expf(ls[0]) * d3 / sqrtf(n2sq);
}

__global__ __launch_bounds__(1024) void softmax_kernel(const float* __restrict__ logits,
                                                       float* __restrict__ out) {
  __shared__ float scr[17];
  const int t = threadIdx.x;
  const int wv = t >> 6, lane = t & 63;
  const float l = (t < NCLS) ? logits[t] : -INFINITY;
  float m = l;
#pragma unroll
  for (int off = 32; off; off >>= 1) m = fmaxf(m, __shfl_xor(m, off, 64));
  if (lane == 0) scr[wv] = m;
  __syncthreads();
  if (wv == 0) {
    float x = (lane < 16) ? scr[lane] : -INFINITY;
#pragma unroll
    for (int off = 8; off; off >>= 1) x = fmaxf(x, __shfl_xor(x, off, 64));
    if (lane == 0) scr[16] = x;
  }
  __syncthreads();
  m = scr[16];
  const float e = (t < NCLS) ? expf(l - m) : 0.0f;
  const float s = block_sum16(e, scr);
  if (t < NCLS) out[t] = e / s;
}

extern "C" void kernel_launch(void* const* d_in, const int* in_sizes, int n_in,
                              void* d_out, int out_size, void* d_ws, size_t ws_size,
                              hipStream_t stream) {
  const float* img = (const float*)d_in[0];
  const float* memp = (const float*)d_in[1];
  const float* gb = (const float*)d_in[2];
  const float* gbk = (const float*)d_in[3];
  const float* gbv = (const float*)d_in[4];
  const float* gffn = (const float*)d_in[5];
  const float* ls = (const float*)d_in[6];
  float* out = (float*)d_out;

  float* s = (float*)d_ws;      // [D]
  float* q = s + D;             // [D]
  float* logits = q + D;        // [NCLS]

  zero_kernel<<<1, D, 0, stream>>>(s);
  colsum_kernel<<<64, D, 0, stream>>>(gb, s);
  qnorm_kernel<<<1, D, 0, stream>>>(img, s, q);
  main_kernel<<<NCLS, D, 0, stream>>>(memp, gbk, gbv, gffn, img, q, ls, logits);
  softmax_kernel<<<1, D, 0, stream>>>(logits, out);
}

// Round 2
// 237.041 us; speedup vs baseline: 1.0193x; 1.0193x over previous
//
#include <hip/hip_runtime.h>
#include <math.h>

#define NCLS 1000
#define MT 33
#define D 1024
#define BETA 5.5f

__device__ __forceinline__ float wave_sum(float v) {
#pragma unroll
  for (int off = 32; off; off >>= 1) v += __shfl_xor(v, off, 64);
  return v;
}

__device__ __forceinline__ float dot4(float4 a, float4 b) {
  return a.x * b.x + a.y * b.y + a.z * b.z + a.w * b.w;
}

// block of 1024 threads (16 waves); scr must hold >=17 floats
__device__ __forceinline__ float block_sum16(float v, volatile float* scr) {
  v = wave_sum(v);
  const int wv = threadIdx.x >> 6, lane = threadIdx.x & 63;
  if (lane == 0) scr[wv] = v;
  __syncthreads();
  if (wv == 0) {
    float x = (lane < 16) ? scr[lane] : 0.0f;
#pragma unroll
    for (int off = 8; off; off >>= 1) x += __shfl_xor(x, off, 64);
    if (lane == 0) scr[16] = x;
  }
  __syncthreads();
  return scr[16];
}

// two independent sums sharing the same two barriers
__device__ __forceinline__ float2 block_sum2(float a, float b, volatile float* scr) {
  a = wave_sum(a);
  b = wave_sum(b);
  const int wv = threadIdx.x >> 6, lane = threadIdx.x & 63;
  if (lane == 0) {
    scr[wv] = a;
    scr[16 + wv] = b;
  }
  __syncthreads();
  if (wv == 0) {
    float x = (lane < 16) ? scr[lane] : 0.0f;
    float y = (lane < 16) ? scr[16 + lane] : 0.0f;
#pragma unroll
    for (int off = 8; off; off >>= 1) {
      x += __shfl_xor(x, off, 64);
      y += __shfl_xor(y, off, 64);
    }
    if (lane == 0) {
      scr[32] = x;
      scr[33] = y;
    }
  }
  __syncthreads();
  return make_float2(scr[32], scr[33]);
}

__global__ __launch_bounds__(1024) void zero_kernel(float* __restrict__ s) {
  s[threadIdx.x] = 0.0f;
}

// column sum of global_bias [NCLS, D] into s[D] (s pre-zeroed)
__global__ __launch_bounds__(1024) void colsum_kernel(const float* __restrict__ gb,
                                                      float* __restrict__ s) {
  const int t = threadIdx.x;
  float p = 0.0f;
  for (int c = blockIdx.x; c < NCLS; c += gridDim.x) p += gb[(size_t)c * D + t];
  atomicAdd(&s[t], p);
}

__global__ __launch_bounds__(1024) void main_kernel(
    const float* __restrict__ memp, const float* __restrict__ gbk,
    const float* __restrict__ gbv, const float* __restrict__ gffn,
    const float* __restrict__ img, const float* __restrict__ s,
    const float* __restrict__ ls, float* __restrict__ logits) {
  __shared__ float red[8 * D];  // 32 KB two-step reduce buffer
  __shared__ float scr[40];
  const int c = blockIdx.x;
  const int t = threadIdx.x;
  const int wv = t >> 6, lane = t & 63;
  const int dbase = lane * 4;

  const float* gbk_c = gbk + (size_t)c * D;
  const float* gbv_c = gbv + (size_t)c * D;

  // ---- q recomputed per wave (each wave's lanes cover all 1024 dims) ----
  float4 qv[4], kv[4], vvr[4];
  float qss = 0.0f;
#pragma unroll
  for (int k = 0; k < 4; ++k) {
    const int d = k * 256 + dbase;
    const float4 iv = *(const float4*)(img + d);
    const float4 sv = *(const float4*)(s + d);
    float4 v;
    v.x = iv.x + sv.x * (1.0f / (float)NCLS);
    v.y = iv.y + sv.y * (1.0f / (float)NCLS);
    v.z = iv.z + sv.z * (1.0f / (float)NCLS);
    v.w = iv.w + sv.w * (1.0f / (float)NCLS);
    qv[k] = v;
    qss += dot4(v, v);
    kv[k] = *(const float4*)(gbk_c + d);
    vvr[k] = *(const float4*)(gbv_c + d);
  }
  qss = wave_sum(qss);
  const float qinv = 1.0f / sqrtf(qss);
#pragma unroll
  for (int k = 0; k < 4; ++k) {
    qv[k].x *= qinv; qv[k].y *= qinv; qv[k].z *= qinv; qv[k].w *= qinv;
  }

  // per-class scalars: ||gbk||^2, ||gbv||^2, q.gbk (redundant per wave)
  float kk = 0.0f, vv2 = 0.0f, qk = 0.0f;
#pragma unroll
  for (int k = 0; k < 4; ++k) {
    kk += dot4(kv[k], kv[k]);
    vv2 += dot4(vvr[k], vvr[k]);
    qk += dot4(qv[k], kv[k]);
  }
  kk = wave_sum(kk);
  vv2 = wave_sum(vv2);
  qk = wave_sum(qk);

  float4 acc[4];
#pragma unroll
  for (int k = 0; k < 4; ++k) acc[k] = make_float4(0.f, 0.f, 0.f, 0.f);
  float Wsum = 0.0f;

  const float* memc = memp + (size_t)c * MT * D;
  for (int m = wv; m < MT; m += 16) {
    float4 mv[4];
#pragma unroll
    for (int k = 0; k < 4; ++k)
      mv[k] = *(const float4*)(memc + (size_t)m * D + k * 256 + dbase);
    float pqm = 0.f, pkm = 0.f, pvm = 0.f, pmm = 0.f;
#pragma unroll
    for (int k = 0; k < 4; ++k) {
      pqm += dot4(qv[k], mv[k]);
      pkm += dot4(kv[k], mv[k]);
      pvm += dot4(vvr[k], mv[k]);
      pmm += dot4(mv[k], mv[k]);
    }
    pqm = wave_sum(pqm);
    pkm = wave_sum(pkm);
    pvm = wave_sum(pvm);
    pmm = wave_sum(pmm);

    // empty row <=> all elements zero <=> sum of squares == 0
    const float nk = sqrtf(pmm + 2.0f * pkm + kk);
    const float cosv = (pqm + qk) / nk;
    const float sim = expf(-BETA * (1.0f - cosv));
    const float nv = sqrtf(pmm + 2.0f * pvm + vv2);
    const float wgt = (pmm == 0.0f) ? 0.0f : sim / nv;
    Wsum += wgt;
#pragma unroll
    for (int k = 0; k < 4; ++k) {
      acc[k].x += wgt * mv[k].x;
      acc[k].y += wgt * mv[k].y;
      acc[k].z += wgt * mv[k].z;
      acc[k].w += wgt * mv[k].w;
    }
  }
  // fold (sum_m w_m) * gbv into each wave's partial (linear, sums correctly)
#pragma unroll
  for (int k = 0; k < 4; ++k) {
    acc[k].x += Wsum * vvr[k].x;
    acc[k].y += Wsum * vvr[k].y;
    acc[k].z += Wsum * vvr[k].z;
    acc[k].w += Wsum * vvr[k].w;
  }

  // ---- two-step cross-wave reduce: 16 -> 8 partials -> per-thread column sum
  if (wv >= 8) {
    float* dst = red + (wv - 8) * D + dbase;
#pragma unroll
    for (int k = 0; k < 4; ++k) *(float4*)(dst + k * 256) = acc[k];
  }
  __syncthreads();
  if (wv < 8) {
    float* ptr = red + wv * D + dbase;
#pragma unroll
    for (int k = 0; k < 4; ++k) {
      const float4 t4 = *(const float4*)(ptr + k * 256);
      acc[k].x += t4.x;
      acc[k].y += t4.y;
      acc[k].z += t4.z;
      acc[k].w += t4.w;
    }
#pragma unroll
    for (int k = 0; k < 4; ++k) *(float4*)(ptr + k * 256) = acc[k];
  }
  __syncthreads();
  float araw = 0.0f;
#pragma unroll
  for (int w = 0; w < 8; ++w) araw += red[w * D + t];

  // ---- stage 2: double l2norm + dot with img ----
  const float n1sq = block_sum16(araw * araw, scr);
  const float a1 = araw / sqrtf(n1sq) + gffn[(size_t)c * D + t];
  const float2 r2 = block_sum2(a1 * a1, a1 * img[t], scr);
  if (t == 0) logits[c] = expf(ls[0]) * r2.y / sqrtf(r2.x);
}

__global__ __launch_bounds__(1024) void softmax_kernel(const float* __restrict__ logits,
                                                       float* __restrict__ out) {
  __shared__ float scr[40];
  const int t = threadIdx.x;
  const int wv = t >> 6, lane = t & 63;
  const float l = (t < NCLS) ? logits[t] : -INFINITY;
  float m = l;
#pragma unroll
  for (int off = 32; off; off >>= 1) m = fmaxf(m, __shfl_xor(m, off, 64));
  if (lane == 0) scr[wv] = m;
  __syncthreads();
  if (wv == 0) {
    float x = (lane < 16) ? scr[lane] : -INFINITY;
#pragma unroll
    for (int off = 8; off; off >>= 1) x = fmaxf(x, __shfl_xor(x, off, 64));
    if (lane == 0) scr[16] = x;
  }
  __syncthreads();
  m = scr[16];
  const float e = (t < NCLS) ? expf(l - m) : 0.0f;
  const float sden = block_sum16(e, scr);
  if (t < NCLS) out[t] = e / sden;
}

extern "C" void kernel_launch(void* const* d_in, const int* in_sizes, int n_in,
                              void* d_out, int out_size, void* d_ws, size_t ws_size,
                              hipStream_t stream) {
  const float* img = (const float*)d_in[0];
  const float* memp = (const float*)d_in[1];
  const float* gb = (const float*)d_in[2];
  const float* gbk = (const float*)d_in[3];
  const float* gbv = (const float*)d_in[4];
  const float* gffn = (const float*)d_in[5];
  const float* ls = (const float*)d_in[6];
  float* out = (float*)d_out;

  float* s = (float*)d_ws;  // [D]
  float* logits = s + D;    // [NCLS]

  zero_kernel<<<1, D, 0, stream>>>(s);
  colsum_kernel<<<64, D, 0, stream>>>(gb, s);
  main_kernel<<<NCLS, D, 0, stream>>>(memp, gbk, gbv, gffn, img, s, ls, logits);
  softmax_kernel<<<1, D, 0, stream>>>(logits, out);
}

// Round 3
// 229.855 us; speedup vs baseline: 1.0512x; 1.0313x over previous
//
#include <hip/hip_runtime.h>
#include <math.h>

#define NCLS 1000
#define MT 33
#define D 1024
#define BETA 5.5f

__device__ __forceinline__ float wave_sum(float v) {
#pragma unroll
  for (int off = 32; off; off >>= 1) v += __shfl_xor(v, off, 64);
  return v;
}

__device__ __forceinline__ float dot4(float4 a, float4 b) {
  return a.x * b.x + a.y * b.y + a.z * b.z + a.w * b.w;
}

// block of 1024 threads (16 waves); scr must hold >=17 floats
__device__ __forceinline__ float block_sum16(float v, volatile float* scr) {
  v = wave_sum(v);
  const int wv = threadIdx.x >> 6, lane = threadIdx.x & 63;
  if (lane == 0) scr[wv] = v;
  __syncthreads();
  if (wv == 0) {
    float x = (lane < 16) ? scr[lane] : 0.0f;
#pragma unroll
    for (int off = 8; off; off >>= 1) x += __shfl_xor(x, off, 64);
    if (lane == 0) scr[16] = x;
  }
  __syncthreads();
  return scr[16];
}

__global__ __launch_bounds__(1024) void zero_kernel(float* __restrict__ s) {
  s[threadIdx.x] = 0.0f;
}

// column sum of global_bias [NCLS, D] into s[D] (s pre-zeroed)
__global__ __launch_bounds__(1024) void colsum_kernel(const float* __restrict__ gb,
                                                      float* __restrict__ s) {
  const int t = threadIdx.x;
  float p = 0.0f;
  for (int c = blockIdx.x; c < NCLS; c += gridDim.x) p += gb[(size_t)c * D + t];
  atomicAdd(&s[t], p);
}

// 256 threads = 4 waves; each wave owns the full D=1024 dims in registers
// (lane l, chunk k -> dim k*256 + l*4 .. +3). One barrier total.
__global__ __launch_bounds__(256, 4) void main_kernel(
    const float* __restrict__ memp, const float* __restrict__ gbk,
    const float* __restrict__ gbv, const float* __restrict__ gffn,
    const float* __restrict__ img, const float* __restrict__ s,
    const float* __restrict__ ls, float* __restrict__ logits) {
  __shared__ float red[4][D];  // 16 KB cross-wave partials
  const int c = blockIdx.x;
  const int t = threadIdx.x;
  const int wv = t >> 6, lane = t & 63;
  const int dbase = lane * 4;

  const float* gbk_c = gbk + (size_t)c * D;
  const float* gbv_c = gbv + (size_t)c * D;

  // ---- q recomputed per wave ----
  float4 qv[4], kv[4], vvr[4];
  float qss = 0.0f;
#pragma unroll
  for (int k = 0; k < 4; ++k) {
    const int d = k * 256 + dbase;
    const float4 iv = *(const float4*)(img + d);
    const float4 sv = *(const float4*)(s + d);
    float4 v;
    v.x = iv.x + sv.x * (1.0f / (float)NCLS);
    v.y = iv.y + sv.y * (1.0f / (float)NCLS);
    v.z = iv.z + sv.z * (1.0f / (float)NCLS);
    v.w = iv.w + sv.w * (1.0f / (float)NCLS);
    qv[k] = v;
    qss += dot4(v, v);
    kv[k] = *(const float4*)(gbk_c + d);
    vvr[k] = *(const float4*)(gbv_c + d);
  }
  qss = wave_sum(qss);
  const float qinv = 1.0f / sqrtf(qss);
#pragma unroll
  for (int k = 0; k < 4; ++k) {
    qv[k].x *= qinv; qv[k].y *= qinv; qv[k].z *= qinv; qv[k].w *= qinv;
  }

  // per-class scalars: ||gbk||^2, ||gbv||^2, q.gbk (redundant per wave)
  float kk = 0.0f, vv2 = 0.0f, qk = 0.0f;
#pragma unroll
  for (int k = 0; k < 4; ++k) {
    kk += dot4(kv[k], kv[k]);
    vv2 += dot4(vvr[k], vvr[k]);
    qk += dot4(qv[k], kv[k]);
  }
  kk = wave_sum(kk);
  vv2 = wave_sum(vv2);
  qk = wave_sum(qk);

  float4 acc[4];
#pragma unroll
  for (int k = 0; k < 4; ++k) acc[k] = make_float4(0.f, 0.f, 0.f, 0.f);
  float Wsum = 0.0f;

  // ---- slot loop: wave wv handles slots wv, wv+4, ... (8-9 iters) ----
  const float* memc = memp + (size_t)c * MT * D;
  for (int m = wv; m < MT; m += 4) {
    float4 mv[4];
#pragma unroll
    for (int k = 0; k < 4; ++k)
      mv[k] = *(const float4*)(memc + (size_t)m * D + k * 256 + dbase);
    float pqm = 0.f, pkm = 0.f, pvm = 0.f, pmm = 0.f;
#pragma unroll
    for (int k = 0; k < 4; ++k) {
      pqm += dot4(qv[k], mv[k]);
      pkm += dot4(kv[k], mv[k]);
      pvm += dot4(vvr[k], mv[k]);
      pmm += dot4(mv[k], mv[k]);
    }
    pqm = wave_sum(pqm);
    pkm = wave_sum(pkm);
    pvm = wave_sum(pvm);
    pmm = wave_sum(pmm);

    // empty row <=> all elements zero <=> sum of squares == 0
    const float nk = sqrtf(pmm + 2.0f * pkm + kk);
    const float cosv = (pqm + qk) / nk;
    const float sim = expf(-BETA * (1.0f - cosv));
    const float nv = sqrtf(pmm + 2.0f * pvm + vv2);
    const float wgt = (pmm == 0.0f) ? 0.0f : sim / nv;
    Wsum += wgt;
#pragma unroll
    for (int k = 0; k < 4; ++k) {
      acc[k].x += wgt * mv[k].x;
      acc[k].y += wgt * mv[k].y;
      acc[k].z += wgt * mv[k].z;
      acc[k].w += wgt * mv[k].w;
    }
  }
  // fold (sum_m w_m) * gbv into each wave's partial (linear, sums correctly)
#pragma unroll
  for (int k = 0; k < 4; ++k) {
    acc[k].x += Wsum * vvr[k].x;
    acc[k].y += Wsum * vvr[k].y;
    acc[k].z += Wsum * vvr[k].z;
    acc[k].w += Wsum * vvr[k].w;
  }

  // ---- one-barrier cross-wave reduce; every wave gets full a_raw ----
#pragma unroll
  for (int k = 0; k < 4; ++k) *(float4*)(&red[wv][k * 256 + dbase]) = acc[k];
  __syncthreads();
#pragma unroll
  for (int k = 0; k < 4; ++k) {
    const float4 a0 = *(const float4*)(&red[0][k * 256 + dbase]);
    const float4 a1 = *(const float4*)(&red[1][k * 256 + dbase]);
    const float4 a2 = *(const float4*)(&red[2][k * 256 + dbase]);
    const float4 a3 = *(const float4*)(&red[3][k * 256 + dbase]);
    acc[k].x = a0.x + a1.x + a2.x + a3.x;
    acc[k].y = a0.y + a1.y + a2.y + a3.y;
    acc[k].z = a0.z + a1.z + a2.z + a3.z;
    acc[k].w = a0.w + a1.w + a2.w + a3.w;
  }

  // ---- stage 2, barrier-free (replicated per wave) ----
  float n1 = 0.0f;
#pragma unroll
  for (int k = 0; k < 4; ++k) n1 += dot4(acc[k], acc[k]);
  n1 = wave_sum(n1);
  const float inv1 = 1.0f / sqrtf(n1);

  const float* gffn_c = gffn + (size_t)c * D;
  float n2 = 0.0f, d3 = 0.0f;
#pragma unroll
  for (int k = 0; k < 4; ++k) {
    const int d = k * 256 + dbase;
    const float4 gf = *(const float4*)(gffn_c + d);
    const float4 iv = *(const float4*)(img + d);
    float4 a1v;
    a1v.x = acc[k].x * inv1 + gf.x;
    a1v.y = acc[k].y * inv1 + gf.y;
    a1v.z = acc[k].z * inv1 + gf.z;
    a1v.w = acc[k].w * inv1 + gf.w;
    n2 += dot4(a1v, a1v);
    d3 += dot4(a1v, iv);
  }
  n2 = wave_sum(n2);
  d3 = wave_sum(d3);
  if (t == 0) logits[c] = expf(ls[0]) * d3 / sqrtf(n2);
}

__global__ __launch_bounds__(1024) void softmax_kernel(const float* __restrict__ logits,
                                                       float* __restrict__ out) {
  __shared__ float scr[40];
  const int t = threadIdx.x;
  const int wv = t >> 6, lane = t & 63;
  const float l = (t < NCLS) ? logits[t] : -INFINITY;
  float m = l;
#pragma unroll
  for (int off = 32; off; off >>= 1) m = fmaxf(m, __shfl_xor(m, off, 64));
  if (lane == 0) scr[wv] = m;
  __syncthreads();
  if (wv == 0) {
    float x = (lane < 16) ? scr[lane] : -INFINITY;
#pragma unroll
    for (int off = 8; off; off >>= 1) x = fmaxf(x, __shfl_xor(x, off, 64));
    if (lane == 0) scr[16] = x;
  }
  __syncthreads();
  m = scr[16];
  const float e = (t < NCLS) ? expf(l - m) : 0.0f;
  const float sden = block_sum16(e, scr);
  if (t < NCLS) out[t] = e / sden;
}

extern "C" void kernel_launch(void* const* d_in, const int* in_sizes, int n_in,
                              void* d_out, int out_size, void* d_ws, size_t ws_size,
                              hipStream_t stream) {
  const float* img = (const float*)d_in[0];
  const float* memp = (const float*)d_in[1];
  const float* gb = (const float*)d_in[2];
  const float* gbk = (const float*)d_in[3];
  const float* gbv = (const float*)d_in[4];
  const float* gffn = (const float*)d_in[5];
  const float* ls = (const float*)d_in[6];
  float* out = (float*)d_out;

  float* s = (float*)d_ws;  // [D]
  float* logits = s + D;    // [NCLS]

  zero_kernel<<<1, D, 0, stream>>>(s);
  colsum_kernel<<<64, D, 0, stream>>>(gb, s);
  main_kernel<<<NCLS, 256, 0, stream>>>(memp, gbk, gbv, gffn, img, s, ls, logits);
  softmax_kernel<<<1, D, 0, stream>>>(logits, out);
}